// Round 1
// baseline (616.473 us; speedup 1.0000x reference)
//
#include <hip/hip_runtime.h>
#include <hip/hip_bf16.h>

typedef __bf16 bf16_t;
typedef __bf16 bf16x4 __attribute__((ext_vector_type(4)));
typedef __bf16 bf16x8 __attribute__((ext_vector_type(8)));
typedef float  f32x4  __attribute__((ext_vector_type(4)));

#define NB      32      // batch
#define NPIX    4096    // 64*64 pixels per sample
#define CIN     512
#define FOUT    512
#define TM      128
#define TN      128
#define BK      32
#define LDPAD   40      // LDS row stride in bf16 elements (32 + 8 pad -> 80B rows, 16B aligned)

// ---------------------------------------------------------------------------
// Pass 1: gather per-batch class weights, transpose [k][n] -> [n][k], cvt bf16.
// wsB[b][n][k] = (bf16) kernel[cls[b]][k][n]
// grid (16 n-tiles, 16 k-tiles, 32 batches), block (32,8)
// ---------------------------------------------------------------------------
__global__ __launch_bounds__(256) void gather_w_kernel(
    const float* __restrict__ kern, const int* __restrict__ cls,
    bf16_t* __restrict__ wsB)
{
    __shared__ float tile[32][33];
    const int n0 = blockIdx.x * 32;
    const int k0 = blockIdx.y * 32;
    const int b  = blockIdx.z;
    const int c  = cls[b];
    const int tx = threadIdx.x;      // 0..31
    const int ty = threadIdx.y;      // 0..7

    const float* src = kern + (long)c * CIN * FOUT;
#pragma unroll
    for (int i = 0; i < 4; i++) {
        int k = k0 + ty + i * 8;
        tile[ty + i * 8][tx] = src[(long)k * FOUT + n0 + tx];
    }
    __syncthreads();
    bf16_t* dst = wsB + (long)b * FOUT * CIN;
#pragma unroll
    for (int i = 0; i < 4; i++) {
        int n = n0 + ty + i * 8;
        dst[(long)n * CIN + k0 + tx] = (bf16_t)tile[tx][ty + i * 8];
    }
}

// ---------------------------------------------------------------------------
// Pass 2: per-batch GEMM. out[b,p,f] = sum_c x[b,p,c] * wsB[b,f,c] + bias[cls[b],f]
// 128x128 tile, BK=32, 4 waves each computing 64x64 via 4x4 of 16x16x32 MFMA.
// ---------------------------------------------------------------------------
__global__ __launch_bounds__(256) void cond_conv_gemm(
    const float*  __restrict__ x,
    const bf16_t* __restrict__ wsB,
    const float*  __restrict__ bias,
    const int*    __restrict__ cls,
    float*        __restrict__ out)
{
    __shared__ bf16_t As[TM * LDPAD];   // [m][k] padded
    __shared__ bf16_t Bs[TN * LDPAD];   // [n][k] padded

    const int bid = blockIdx.x;
    const int n_t = bid & 3;            // 4 n-tiles (fastest: adjacent blocks share A tile)
    const int m_t = (bid >> 2) & 31;    // 32 m-tiles
    const int b   = bid >> 7;           // 32 batches

    const long x_base = (long)b * NPIX * CIN + (long)m_t * TM * CIN;
    const long w_base = (long)b * FOUT * CIN;
    const int  n0     = n_t * TN;

    const int t    = threadIdx.x;
    const int wave = t >> 6;
    const int lane = t & 63;
    const int wm   = (wave >> 1) * 64;  // wave m-offset in tile
    const int wn   = (wave & 1) * 64;   // wave n-offset in tile
    const int l15  = lane & 15;
    const int quad = lane >> 4;

    f32x4 acc[4][4];
#pragma unroll
    for (int i = 0; i < 4; i++)
#pragma unroll
        for (int j = 0; j < 4; j++)
            acc[i][j] = (f32x4){0.f, 0.f, 0.f, 0.f};

    for (int k0 = 0; k0 < CIN; k0 += BK) {
        // ---- stage A: 128x32 fp32 -> bf16 LDS ----
#pragma unroll
        for (int g = 0; g < 4; g++) {
            int chunk = t + g * 256;          // 1024 chunks of 4 floats
            int m  = chunk >> 3;
            int kc = (chunk & 7) << 2;
            float4 v = *(const float4*)(x + x_base + (long)m * CIN + k0 + kc);
            bf16x4 h;
            h[0] = (bf16_t)v.x; h[1] = (bf16_t)v.y;
            h[2] = (bf16_t)v.z; h[3] = (bf16_t)v.w;
            *(bf16x4*)(&As[m * LDPAD + kc]) = h;
        }
        // ---- stage B: 128x32 bf16 from workspace ----
#pragma unroll
        for (int g = 0; g < 2; g++) {
            int chunk = t + g * 256;          // 512 chunks of 8 bf16
            int n  = chunk >> 2;
            int kc = (chunk & 3) << 3;
            bf16x8 v = *(const bf16x8*)(wsB + w_base + (long)(n0 + n) * CIN + k0 + kc);
            *(bf16x8*)(&Bs[n * LDPAD + kc]) = v;
        }
        __syncthreads();

        // ---- fragments + MFMA ----
        bf16x8 af[4], bf[4];
#pragma unroll
        for (int i = 0; i < 4; i++)
            af[i] = *(const bf16x8*)(&As[(wm + i * 16 + l15) * LDPAD + quad * 8]);
#pragma unroll
        for (int i = 0; i < 4; i++)
            bf[i] = *(const bf16x8*)(&Bs[(wn + i * 16 + l15) * LDPAD + quad * 8]);
#pragma unroll
        for (int mi = 0; mi < 4; mi++)
#pragma unroll
            for (int ni = 0; ni < 4; ni++)
                acc[mi][ni] = __builtin_amdgcn_mfma_f32_16x16x32_bf16(
                    af[mi], bf[ni], acc[mi][ni], 0, 0, 0);
        __syncthreads();
    }

    // ---- epilogue: C layout col=lane&15, row=quad*4+reg ----
    const int c = cls[b];
    const long out_base = (long)b * NPIX * FOUT + (long)(m_t * TM) * FOUT + n0;
#pragma unroll
    for (int ni = 0; ni < 4; ni++) {
        float bv = bias[(long)c * FOUT + n0 + wn + ni * 16 + l15];
        int col = wn + ni * 16 + l15;
#pragma unroll
        for (int mi = 0; mi < 4; mi++) {
#pragma unroll
            for (int r = 0; r < 4; r++) {
                int row = wm + mi * 16 + quad * 4 + r;
                out[out_base + (long)row * FOUT + col] = acc[mi][ni][r] + bv;
            }
        }
    }
}

// ---------------------------------------------------------------------------
// Fallback (only if ws too small): naive fp32, correct but slow.
// ---------------------------------------------------------------------------
__global__ __launch_bounds__(256) void naive_kernel(
    const float* __restrict__ x, const float* __restrict__ kern,
    const float* __restrict__ bias, const int* __restrict__ cls,
    float* __restrict__ out)
{
    long i = (long)blockIdx.x * 256 + threadIdx.x;   // over 67.1M outputs
    if (i >= (long)NB * NPIX * FOUT) return;
    int f = (int)(i % FOUT);
    long p = i / FOUT;
    int b = (int)(p / NPIX);
    int c = cls[b];
    const float* xr = x + p * CIN;
    const float* wc = kern + (long)c * CIN * FOUT + f;
    float acc = 0.f;
    for (int k = 0; k < CIN; k++) acc += xr[k] * wc[(long)k * FOUT];
    out[i] = acc + bias[(long)c * FOUT + f];
}

extern "C" void kernel_launch(void* const* d_in, const int* in_sizes, int n_in,
                              void* d_out, int out_size, void* d_ws, size_t ws_size,
                              hipStream_t stream)
{
    const float* x    = (const float*)d_in[0];
    const int*   cls  = (const int*)d_in[1];
    const float* kern = (const float*)d_in[2];
    const float* bias = (const float*)d_in[3];
    float*       out  = (float*)d_out;

    const size_t ws_need = (size_t)NB * FOUT * CIN * sizeof(bf16_t);  // 16.8 MB
    if (ws_size >= ws_need) {
        bf16_t* wsB = (bf16_t*)d_ws;
        gather_w_kernel<<<dim3(FOUT / 32, CIN / 32, NB), dim3(32, 8), 0, stream>>>(
            kern, cls, wsB);
        cond_conv_gemm<<<NB * (NPIX / TM) * (FOUT / TN), 256, 0, stream>>>(
            x, wsB, bias, cls, out);
    } else {
        long n = (long)NB * NPIX * FOUT;
        naive_kernel<<<(int)((n + 255) / 256), 256, 0, stream>>>(x, kern, bias, cls, out);
    }
}